// Round 5
// baseline (490.097 us; speedup 1.0000x reference)
//
#include <hip/hip_runtime.h>
#include <stdint.h>

#define N_NODES 50000
#define E_EDGES 800000
#define HID 128
#define NGROUP 25000           // E_EDGES / 32
#define BE 128                 // edges per block (fallback kernel)
#define XS_STRIDE 264
#define YS_STRIDE 136
#define HS_STRIDE 132          // 66 words ≡ 2 mod 32 -> 2-way (free) A reads

typedef unsigned short u16;
typedef unsigned char u8;
typedef __attribute__((ext_vector_type(8))) short svec8;
typedef __attribute__((ext_vector_type(16))) float fvec16;
typedef __attribute__((ext_vector_type(4))) unsigned uvec4;
typedef __attribute__((ext_vector_type(2))) unsigned uvec2;
typedef __attribute__((ext_vector_type(2))) float fvec2;

union frag_u { uvec4 u; svec8 s; };

__device__ __forceinline__ float bf2f(u16 u) {
    union { unsigned int i; float f; } v; v.i = ((unsigned int)u) << 16; return v.f;
}
__device__ __forceinline__ u16 f2bf(float f) {
    union { float f; unsigned int i; } v; v.f = f;
    unsigned int u = v.i;
    return (u16)((u + 0x7fffu + ((u >> 16) & 1u)) >> 16);   // RNE
}
__device__ __forceinline__ unsigned f2u(float f) {
    union { float f; unsigned i; } v; v.f = f; return v.i;
}
__device__ __forceinline__ float lo16(unsigned u) {
    union { unsigned i; float f; } v; v.i = u << 16; return v.f;
}
__device__ __forceinline__ float hi16(unsigned u) {
    union { unsigned i; float f; } v; v.i = u & 0xFFFF0000u; return v.f;
}
__device__ __forceinline__ float silu_f(float x) {
    return x * __builtin_amdgcn_rcpf(1.0f + __expf(-x));
}
__device__ __forceinline__ float ldf(const void* p, size_t i, int is_bf) {
    return is_bf ? bf2f(((const u16*)p)[i]) : ((const float*)p)[i];
}
__device__ __forceinline__ int ldi(const void* p, size_t i, int is_i64) {
    return is_i64 ? ((const int*)p)[2 * i] : ((const int*)p)[i];
}

// ---- dtype detection: flags[0]=floats-are-bf16, flags[1]=edge_index-is-int64 ----
__global__ void detect_kernel(const void* __restrict__ h,
                              const void* __restrict__ eidx,
                              int* __restrict__ flags) {
    __shared__ int cnt_bf, cnt_i64;
    if (threadIdx.x == 0) { cnt_bf = 0; cnt_i64 = 0; }
    __syncthreads();
    const int t = threadIdx.x;
    unsigned u = ((const u16*)h)[2 * t];
    unsigned e = (u >> 7) & 0xFFu;
    int plaus = (e >= 100u && e <= 140u) ? 1 : 0;
    int z = (((const int*)eidx)[2 * t + 1] == 0) ? 1 : 0;
    atomicAdd(&cnt_bf, plaus);
    atomicAdd(&cnt_i64, z);
    __syncthreads();
    if (t == 0) { flags[0] = (cnt_bf >= 128); flags[1] = (cnt_i64 >= 128); }
}

// ---- W transpose + w1l(bf16): W1[257][128]->W1t[128][256], W2->W2t, W1[256][:]->w1lb ----
__global__ void transpose_w(const void* __restrict__ W1, const void* __restrict__ W2,
                            u16* __restrict__ W1t, u16* __restrict__ W2t,
                            u16* __restrict__ w1lb, const int* __restrict__ flags) {
    const int is_bf = flags[0];
    int n = blockIdx.x;        // 0..127 output column
    int k = threadIdx.x;       // 0..255
    W1t[n * 256 + k] = f2bf(ldf(W1, (size_t)k * 128 + n, is_bf));
    if (k < 128) W2t[n * 128 + k] = f2bf(ldf(W2, (size_t)k * 128 + n, is_bf));
    if (n == 0 && k < 128) w1lb[k] = f2bf(ldf(W1, (size_t)256 * 128 + k, is_bf));
}

// ---- precompute P[node][0:128]=fp8(h@W1a+b1), P[node][128:256]=fp8(h@W1b) ----
__global__ __launch_bounds__(256) void precompute_p(
    const void* __restrict__ h, const void* __restrict__ b1,
    const u16* __restrict__ W1t, const int* __restrict__ flags,
    u8* __restrict__ P)
{
    __shared__ __align__(16) union SMem {
        u16 Hs[128 * HS_STRIDE];
        float Cs[128 * 256];
    } sm;                                           // 128 KB
    const int tid = threadIdx.x;
    const int is_bf = flags[0];
    const int base = blockIdx.x * 128;
    {
        const int rr = tid >> 5, c = tid & 31;
        for (int it = 0; it < 16; ++it) {
            int row = it * 8 + rr;
            int node = base + row; if (node > N_NODES - 1) node = N_NODES - 1;
            u16* dst = &sm.Hs[row * HS_STRIDE + c * 4];
            if (is_bf) {
                *(uint2*)dst = *(const uint2*)((const u16*)h + (size_t)node * HID + c * 4);
            } else {
                float4 v = *(const float4*)((const float*)h + (size_t)node * HID + c * 4);
                uint2 w;
                w.x = (unsigned)f2bf(v.x) | ((unsigned)f2bf(v.y) << 16);
                w.y = (unsigned)f2bf(v.z) | ((unsigned)f2bf(v.w) << 16);
                *(uint2*)dst = w;
            }
        }
    }
    __syncthreads();
    const int lane = tid & 63, wv = tid >> 6, l31 = lane & 31, hi = lane >> 5;
    // wave wv: rows [wv*32, wv*32+32) x all 256 output cols (8 strips)
    fvec16 acc[8] = {};
    for (int ks = 0; ks < 8; ++ks) {
        const int kk = ks * 16 + hi * 8;
        svec8 af = *(const svec8*)(&sm.Hs[(wv * 32 + l31) * HS_STRIDE + kk]);
        #pragma unroll
        for (int t = 0; t < 8; ++t) {
            const int n = t * 32 + l31;
            const u16* bp = (t < 4) ? (W1t + n * 256 + kk)
                                    : (W1t + (n - 128) * 256 + 128 + kk);
            svec8 bf = *(const svec8*)bp;
            acc[t] = __builtin_amdgcn_mfma_f32_32x32x16_bf16(af, bf, acc[t], 0, 0, 0);
        }
    }
    __syncthreads();                 // all waves done reading Hs before Cs overwrite
    #pragma unroll
    for (int t = 0; t < 8; ++t) {
        const int n = t * 32 + l31;
        const float bias = (t < 4) ? ldf(b1, n, is_bf) : 0.0f;
        #pragma unroll
        for (int r = 0; r < 16; ++r) {
            int m = (r & 3) + 8 * (r >> 2) + 4 * hi;
            sm.Cs[(wv * 32 + m) * 256 + n] = acc[t][r] + bias;
        }
    }
    __syncthreads();
    // pack fp8 + coalesced 16B stores: 16 threads per node row
    #pragma unroll
    for (int i = 0; i < 8; ++i) {
        int row = i * 16 + (tid >> 4);
        int node = base + row;
        if (node < N_NODES) {
            const float* src = &sm.Cs[row * 256 + (tid & 15) * 16];
            uvec4 outv;
            #pragma unroll
            for (int d = 0; d < 4; ++d) {
                int w = __builtin_amdgcn_cvt_pk_fp8_f32(src[d * 4 + 0], src[d * 4 + 1], 0, false);
                w     = __builtin_amdgcn_cvt_pk_fp8_f32(src[d * 4 + 2], src[d * 4 + 3], w, true);
                outv[d] = (unsigned)w;
            }
            *(uvec4*)(P + (size_t)node * 256 + (tid & 15) * 16) = outv;
        }
    }
}

// ---- edge kernel: gather fp8 P -> add+silu (A-frags in reg) -> W2 MFMA -> phi -> scatter ----
__global__ __launch_bounds__(256, 4) void egnn_edge_p(
    const u8* __restrict__ P, const void* __restrict__ coord_diff,
    const void* __restrict__ edge_attr, const void* __restrict__ edge_index,
    const u16* __restrict__ w1lb, const void* __restrict__ b2,
    const void* __restrict__ W3, const u16* __restrict__ W2t,
    float* __restrict__ agg, const int* __restrict__ flags)
{
    __shared__ __align__(16) u16 W2f[16384];   // frag-ordered W2 (32 KB)
    const int tid = threadIdx.x;
    #pragma unroll
    for (int i = 0; i < 8; ++i) {              // stage: f = t*512+ks*64+hi*32+l31, dst=f*8
        int f = i * 256 + tid;
        int t = f >> 9, ks = (f >> 6) & 7, fh = (f >> 5) & 1, fl = f & 31;
        *(svec8*)(&W2f[f * 8]) = *(const svec8*)(W2t + (t * 32 + fl) * 128 + ks * 16 + fh * 8);
    }
    const int is_bf = flags[0], is_i64 = flags[1];
    const int lane = tid & 63, wv = tid >> 6, l31 = lane & 31, hi = lane >> 5;
    __syncthreads();                           // last barrier; main loop is wave-autonomous

    uvec4 w1l[8];
    #pragma unroll
    for (int ks = 0; ks < 8; ++ks) w1l[ks] = *(const uvec4*)(w1lb + ks * 16 + hi * 8);
    float b2c[4], w3c[4];
    #pragma unroll
    for (int t = 0; t < 4; ++t) {
        int c = t * 32 + l31;
        b2c[t] = ldf(b2, c, is_bf);
        w3c[t] = ldf(W3, c, is_bf);
    }

    const int wid = blockIdx.x * 4 + wv, nw = gridDim.x * 4;
    for (int g = wid; g < NGROUP; g += nw) {
        const int e   = g * 32 + l31;
        const int row = ldi(edge_index, (size_t)e, is_i64);
        const int col = ldi(edge_index, (size_t)E_EDGES + e, is_i64);
        const float ea = ldf(edge_attr, (size_t)e, is_bf);

        uvec2 p1[8], p2[8];
        #pragma unroll
        for (int ks = 0; ks < 8; ++ks) {
            const int kk = ks * 16 + hi * 8;
            p1[ks] = *(const uvec2*)(P + (size_t)row * 256 + kk);
            p2[ks] = *(const uvec2*)(P + (size_t)col * 256 + 128 + kk);
        }
        frag_u af[8];
        #pragma unroll
        for (int ks = 0; ks < 8; ++ks) {
            float q1[8], q2[8];
            #pragma unroll
            for (int d = 0; d < 2; ++d) {
                fvec2 t0 = __builtin_amdgcn_cvt_pk_f32_fp8((int)p1[ks][d], false);
                fvec2 t1 = __builtin_amdgcn_cvt_pk_f32_fp8((int)p1[ks][d], true);
                q1[d * 4 + 0] = t0[0]; q1[d * 4 + 1] = t0[1];
                q1[d * 4 + 2] = t1[0]; q1[d * 4 + 3] = t1[1];
                fvec2 s0 = __builtin_amdgcn_cvt_pk_f32_fp8((int)p2[ks][d], false);
                fvec2 s1 = __builtin_amdgcn_cvt_pk_f32_fp8((int)p2[ks][d], true);
                q2[d * 4 + 0] = s0[0]; q2[d * 4 + 1] = s0[1];
                q2[d * 4 + 2] = s1[0]; q2[d * 4 + 3] = s1[1];
            }
            #pragma unroll
            for (int p = 0; p < 4; ++p) {
                const unsigned uw = w1l[ks][p];
                float xl = q1[2 * p]     + q2[2 * p]     + ea * lo16(uw);
                float xh = q1[2 * p + 1] + q2[2 * p + 1] + ea * hi16(uw);
                float yl = silu_f(xl), yh = silu_f(xh);
                af[ks].u[p] = (f2u(yl) >> 16) | (f2u(yh) & 0xFFFF0000u);  // trunc pack
            }
        }
        fvec16 acc[4] = {};
        #pragma unroll
        for (int ks = 0; ks < 8; ++ks) {
            #pragma unroll
            for (int t = 0; t < 4; ++t) {
                svec8 bf = *(const svec8*)(&W2f[((t * 8 + ks) * 2 + hi) * 256 + l31 * 8]);
                acc[t] = __builtin_amdgcn_mfma_f32_32x32x16_bf16(af[ks].s, bf, acc[t], 0, 0, 0);
            }
        }
        float s[16];
        #pragma unroll
        for (int r = 0; r < 16; ++r) s[r] = 0.0f;
        #pragma unroll
        for (int t = 0; t < 4; ++t)
            #pragma unroll
            for (int r = 0; r < 16; ++r)
                s[r] += silu_f(acc[t][r] + b2c[t]) * w3c[t];
        #pragma unroll
        for (int r = 0; r < 16; ++r) {          // butterfly over each 32-lane half
            s[r] += __shfl_xor(s[r], 1);
            s[r] += __shfl_xor(s[r], 2);
            s[r] += __shfl_xor(s[r], 4);
            s[r] += __shfl_xor(s[r], 8);
            s[r] += __shfl_xor(s[r], 16);
        }
        float phi = 0.0f;
        #pragma unroll
        for (int r = 0; r < 16; ++r) if (l31 == r) phi = s[r];
        if (l31 < 16) {
            const int em = (l31 & 3) + 8 * (l31 >> 2) + 4 * hi;   // C-layout row
            const int eg = g * 32 + em;
            const int r2 = ldi(edge_index, (size_t)eg, is_i64);
            const float cx = ldf(coord_diff, (size_t)eg * 3 + 0, is_bf);
            const float cy = ldf(coord_diff, (size_t)eg * 3 + 1, is_bf);
            const float cz = ldf(coord_diff, (size_t)eg * 3 + 2, is_bf);
            atomicAdd(&agg[r2 * 3 + 0], cx * phi);
            atomicAdd(&agg[r2 * 3 + 1], cy * phi);
            atomicAdd(&agg[r2 * 3 + 2], cz * phi);
        }
    }
}

// ================= fallback (round-3, verified) when ws too small =================
__global__ __launch_bounds__(256, 2) void egnn_edge_kernel(
    const void* __restrict__ h, const void* __restrict__ coord_diff,
    const void* __restrict__ edge_attr, const void* __restrict__ edge_index,
    const void* __restrict__ W1, const void* __restrict__ b1,
    const void* __restrict__ b2, const void* __restrict__ W3,
    const u16* __restrict__ W1t, const u16* __restrict__ W2t,
    float* __restrict__ agg, const int* __restrict__ flags)
{
    __shared__ __align__(16) u16 Xs[BE * XS_STRIDE];
    __shared__ int   rows_s[BE];
    __shared__ int   cols_s[BE];
    __shared__ float ea_s[BE];
    __shared__ float b1_s[HID], b2_s[HID], w1l_s[HID], w3_s[HID];

    const int tid = threadIdx.x;
    const int e0  = blockIdx.x * BE;
    const int is_bf  = flags[0];
    const int is_i64 = flags[1];

    if (tid < BE) {
        rows_s[tid] = ldi(edge_index, (size_t)(e0 + tid), is_i64);
        cols_s[tid] = ldi(edge_index, (size_t)(E_EDGES + e0 + tid), is_i64);
        ea_s[tid]   = ldf(edge_attr, (size_t)(e0 + tid), is_bf);
    }
    if (tid < HID) {
        b1_s[tid]  = ldf(b1, tid, is_bf);
        b2_s[tid]  = ldf(b2, tid, is_bf);
        w1l_s[tid] = ldf(W1, (size_t)256 * 128 + tid, is_bf);
        w3_s[tid]  = ldf(W3, tid, is_bf);
    }
    __syncthreads();
    {
        const int gg = tid >> 4, c = tid & 15;
        #pragma unroll
        for (int it = 0; it < 16; ++it) {
            int hr = it * 16 + gg;
            int e = hr >> 1, half = hr & 1;
            int src = half ? cols_s[e] : rows_s[e];
            svec8 v;
            if (is_bf) {
                v = *(const svec8*)((const u16*)h + (size_t)src * HID + c * 8);
            } else {
                const float* hf = (const float*)h + (size_t)src * HID + c * 8;
                float4 va = *(const float4*)hf;
                float4 vb = *(const float4*)(hf + 4);
                v[0] = (short)f2bf(va.x); v[1] = (short)f2bf(va.y);
                v[2] = (short)f2bf(va.z); v[3] = (short)f2bf(va.w);
                v[4] = (short)f2bf(vb.x); v[5] = (short)f2bf(vb.y);
                v[6] = (short)f2bf(vb.z); v[7] = (short)f2bf(vb.w);
            }
            *(svec8*)(&Xs[e * XS_STRIDE + half * 128 + c * 8]) = v;
        }
    }
    __syncthreads();
    const int lane = tid & 63;
    const int wv   = tid >> 6;
    const int l31  = lane & 31, hi = lane >> 5;
    const int col  = wv * 32 + l31;

    fvec16 acc[4] = {};
    for (int ks = 0; ks < 16; ++ks) {
        const int kk = ks * 16 + hi * 8;
        svec8 bfrag = *(const svec8*)(W1t + col * 256 + kk);
        #pragma unroll
        for (int mt = 0; mt < 4; ++mt) {
            svec8 afrag = *(const svec8*)(&Xs[(mt * 32 + l31) * XS_STRIDE + kk]);
            acc[mt] = __builtin_amdgcn_mfma_f32_32x32x16_bf16(afrag, bfrag, acc[mt], 0, 0, 0);
        }
    }
    __syncthreads();
    u16* Ys = Xs;
    #pragma unroll
    for (int mt = 0; mt < 4; ++mt)
        #pragma unroll
        for (int r = 0; r < 16; ++r) {
            int row = mt * 32 + (r & 3) + 8 * (r >> 2) + 4 * hi;
            float v = acc[mt][r] + ea_s[row] * w1l_s[col] + b1_s[col];
            Ys[row * YS_STRIDE + col] = f2bf(silu_f(v));
        }
    __syncthreads();
    fvec16 acc2[4] = {};
    for (int ks = 0; ks < 8; ++ks) {
        const int kk = ks * 16 + hi * 8;
        svec8 bfrag = *(const svec8*)(W2t + col * 128 + kk);
        #pragma unroll
        for (int mt = 0; mt < 4; ++mt) {
            svec8 afrag = *(const svec8*)(&Ys[(mt * 32 + l31) * YS_STRIDE + kk]);
            acc2[mt] = __builtin_amdgcn_mfma_f32_32x32x16_bf16(afrag, bfrag, acc2[mt], 0, 0, 0);
        }
    }
    __syncthreads();
    #pragma unroll
    for (int mt = 0; mt < 4; ++mt)
        #pragma unroll
        for (int r = 0; r < 16; ++r) {
            int row = mt * 32 + (r & 3) + 8 * (r >> 2) + 4 * hi;
            float v = acc2[mt][r] + b2_s[col];
            Ys[row * YS_STRIDE + col] = f2bf(silu_f(v));
        }
    __syncthreads();
    if (tid < BE) {
        const int e = tid;
        float phi = 0.0f;
        #pragma unroll
        for (int j = 0; j < 16; ++j) {
            svec8 x = *(const svec8*)(&Ys[e * YS_STRIDE + j * 8]);
            #pragma unroll
            for (int t = 0; t < 8; ++t)
                phi += bf2f((u16)x[t]) * w3_s[j * 8 + t];
        }
        const size_t ei = (size_t)(e0 + e);
        const int r = rows_s[e];
        atomicAdd(&agg[r * 3 + 0], ldf(coord_diff, ei * 3 + 0, is_bf) * phi);
        atomicAdd(&agg[r * 3 + 1], ldf(coord_diff, ei * 3 + 1, is_bf) * phi);
        atomicAdd(&agg[r * 3 + 2], ldf(coord_diff, ei * 3 + 2, is_bf) * phi);
    }
}

// ---- finalize: out = coord + agg/100, written in the input float dtype ----
__global__ void finalize_kernel(const void* __restrict__ coord,
                                const float* __restrict__ agg,
                                void* __restrict__ out,
                                const int* __restrict__ flags) {
    const int is_bf = flags[0];
    int i = blockIdx.x * blockDim.x + threadIdx.x;
    if (i < N_NODES * 3) {
        float v = ldf(coord, i, is_bf) + agg[i] * 0.01f;
        if (is_bf) ((u16*)out)[i] = f2bf(v);
        else       ((float*)out)[i] = v;
    }
}

extern "C" void kernel_launch(void* const* d_in, const int* in_sizes, int n_in,
                              void* d_out, int out_size, void* d_ws, size_t ws_size,
                              hipStream_t stream) {
    const void* h          = d_in[0];
    const void* coord      = d_in[1];
    const void* coord_diff = d_in[2];
    // d_in[3] = coord_cross (unused)
    const void* edge_attr  = d_in[4];
    const void* edge_index = d_in[5];
    const void* W1 = d_in[6];
    const void* b1 = d_in[7];
    const void* W2 = d_in[8];
    const void* b2 = d_in[9];
    const void* W3 = d_in[10];

    char* ws    = (char*)d_ws;
    float* agg  = (float*)ws;                        // 600000 B
    u16* W1t    = (u16*)(ws + 600064);               // 65536 B
    u16* W2t    = (u16*)(ws + 665600);               // 32768 B
    int* flags  = (int*)(ws + 698368);               // 16 B
    u16* w1lb   = (u16*)(ws + 698432);               // 256 B
    u8* P       = (u8*)(ws + 698880);                // 12,800,000 B (fp8)
    const size_t NEED = 698880 + (size_t)N_NODES * 256;

    detect_kernel<<<dim3(1), dim3(256), 0, stream>>>(h, edge_index, flags);
    hipMemsetAsync(agg, 0, N_NODES * 3 * sizeof(float), stream);
    transpose_w<<<dim3(128), dim3(256), 0, stream>>>(W1, W2, W1t, W2t, w1lb, flags);

    if (ws_size >= NEED) {
        precompute_p<<<dim3((N_NODES + 127) / 128), dim3(256), 0, stream>>>(
            h, b1, W1t, flags, P);
        egnn_edge_p<<<dim3(1024), dim3(256), 0, stream>>>(
            P, coord_diff, edge_attr, edge_index, w1lb, b2, W3, W2t, agg, flags);
    } else {
        egnn_edge_kernel<<<dim3(E_EDGES / BE), dim3(256), 0, stream>>>(
            h, coord_diff, edge_attr, edge_index, W1, b1, b2, W3, W1t, W2t, agg, flags);
    }
    finalize_kernel<<<dim3((N_NODES * 3 + 255) / 256), dim3(256), 0, stream>>>(coord, agg, d_out, flags);
}

// Round 6
// 338.853 us; speedup vs baseline: 1.4463x; 1.4463x over previous
//
#include <hip/hip_runtime.h>
#include <stdint.h>

#define N_NODES 50000
#define E_EDGES 800000
#define HID 128
#define NGROUP 25000           // E_EDGES / 32
#define BE 128                 // edges per block (fallback kernel)
#define XS_STRIDE 264
#define YS_STRIDE 136
#define HS_STRIDE 132          // 66 words ≡ 2 mod 32 -> 2-way (free) A reads

typedef unsigned short u16;
typedef unsigned char u8;
typedef __attribute__((ext_vector_type(8))) short svec8;
typedef __attribute__((ext_vector_type(16))) float fvec16;
typedef __attribute__((ext_vector_type(4))) unsigned uvec4;
typedef __attribute__((ext_vector_type(2))) unsigned uvec2;
typedef __attribute__((ext_vector_type(2))) float fvec2;

union frag_u { uvec4 u; svec8 s; };

__device__ __forceinline__ float bf2f(u16 u) {
    union { unsigned int i; float f; } v; v.i = ((unsigned int)u) << 16; return v.f;
}
__device__ __forceinline__ u16 f2bf(float f) {
    union { float f; unsigned int i; } v; v.f = f;
    unsigned int u = v.i;
    return (u16)((u + 0x7fffu + ((u >> 16) & 1u)) >> 16);   // RNE
}
__device__ __forceinline__ unsigned f2u(float f) {
    union { float f; unsigned i; } v; v.f = f; return v.i;
}
__device__ __forceinline__ float lo16(unsigned u) {
    union { unsigned i; float f; } v; v.i = u << 16; return v.f;
}
__device__ __forceinline__ float hi16(unsigned u) {
    union { unsigned i; float f; } v; v.i = u & 0xFFFF0000u; return v.f;
}
__device__ __forceinline__ float silu_f(float x) {
    return x * __builtin_amdgcn_rcpf(1.0f + __expf(-x));
}
__device__ __forceinline__ float ldf(const void* p, size_t i, int is_bf) {
    return is_bf ? bf2f(((const u16*)p)[i]) : ((const float*)p)[i];
}
__device__ __forceinline__ int ldi(const void* p, size_t i, int is_i64) {
    return is_i64 ? ((const int*)p)[2 * i] : ((const int*)p)[i];
}

// ---- dtype detection: flags[0]=floats-are-bf16, flags[1]=edge_index-is-int64 ----
__global__ void detect_kernel(const void* __restrict__ h,
                              const void* __restrict__ eidx,
                              int* __restrict__ flags) {
    __shared__ int cnt_bf, cnt_i64;
    if (threadIdx.x == 0) { cnt_bf = 0; cnt_i64 = 0; }
    __syncthreads();
    const int t = threadIdx.x;
    unsigned u = ((const u16*)h)[2 * t];
    unsigned e = (u >> 7) & 0xFFu;
    int plaus = (e >= 100u && e <= 140u) ? 1 : 0;
    int z = (((const int*)eidx)[2 * t + 1] == 0) ? 1 : 0;
    atomicAdd(&cnt_bf, plaus);
    atomicAdd(&cnt_i64, z);
    __syncthreads();
    if (t == 0) { flags[0] = (cnt_bf >= 128); flags[1] = (cnt_i64 >= 128); }
}

// ---- W transpose + w1l(bf16): W1[257][128]->W1t[128][256], W2->W2t, W1[256][:]->w1lb ----
__global__ void transpose_w(const void* __restrict__ W1, const void* __restrict__ W2,
                            u16* __restrict__ W1t, u16* __restrict__ W2t,
                            u16* __restrict__ w1lb, const int* __restrict__ flags) {
    const int is_bf = flags[0];
    int n = blockIdx.x;        // 0..127 output column
    int k = threadIdx.x;       // 0..255
    W1t[n * 256 + k] = f2bf(ldf(W1, (size_t)k * 128 + n, is_bf));
    if (k < 128) W2t[n * 128 + k] = f2bf(ldf(W2, (size_t)k * 128 + n, is_bf));
    if (n == 0 && k < 128) w1lb[k] = f2bf(ldf(W1, (size_t)256 * 128 + k, is_bf));
}

// ---- precompute P[node][0:128]=fp8(h@W1a+b1), P[node][128:256]=fp8(h@W1b) ----
__global__ __launch_bounds__(256) void precompute_p(
    const void* __restrict__ h, const void* __restrict__ b1,
    const u16* __restrict__ W1t, const int* __restrict__ flags,
    u8* __restrict__ P)
{
    __shared__ __align__(16) union SMem {
        u16 Hs[128 * HS_STRIDE];
        float Cs[128 * 256];
    } sm;                                           // 128 KB
    const int tid = threadIdx.x;
    const int is_bf = flags[0];
    const int base = blockIdx.x * 128;
    {
        const int rr = tid >> 5, c = tid & 31;
        for (int it = 0; it < 16; ++it) {
            int row = it * 8 + rr;
            int node = base + row; if (node > N_NODES - 1) node = N_NODES - 1;
            u16* dst = &sm.Hs[row * HS_STRIDE + c * 4];
            if (is_bf) {
                *(uint2*)dst = *(const uint2*)((const u16*)h + (size_t)node * HID + c * 4);
            } else {
                float4 v = *(const float4*)((const float*)h + (size_t)node * HID + c * 4);
                uint2 w;
                w.x = (unsigned)f2bf(v.x) | ((unsigned)f2bf(v.y) << 16);
                w.y = (unsigned)f2bf(v.z) | ((unsigned)f2bf(v.w) << 16);
                *(uint2*)dst = w;
            }
        }
    }
    __syncthreads();
    const int lane = tid & 63, wv = tid >> 6, l31 = lane & 31, hi = lane >> 5;
    // wave wv: rows [wv*32, wv*32+32) x all 256 output cols (8 strips)
    fvec16 acc[8] = {};
    for (int ks = 0; ks < 8; ++ks) {
        const int kk = ks * 16 + hi * 8;
        svec8 af = *(const svec8*)(&sm.Hs[(wv * 32 + l31) * HS_STRIDE + kk]);
        #pragma unroll
        for (int t = 0; t < 8; ++t) {
            const int n = t * 32 + l31;
            const u16* bp = (t < 4) ? (W1t + n * 256 + kk)
                                    : (W1t + (n - 128) * 256 + 128 + kk);
            svec8 bf = *(const svec8*)bp;
            acc[t] = __builtin_amdgcn_mfma_f32_32x32x16_bf16(af, bf, acc[t], 0, 0, 0);
        }
    }
    __syncthreads();                 // all waves done reading Hs before Cs overwrite
    #pragma unroll
    for (int t = 0; t < 8; ++t) {
        const int n = t * 32 + l31;
        const float bias = (t < 4) ? ldf(b1, n, is_bf) : 0.0f;
        #pragma unroll
        for (int r = 0; r < 16; ++r) {
            int m = (r & 3) + 8 * (r >> 2) + 4 * hi;
            sm.Cs[(wv * 32 + m) * 256 + n] = acc[t][r] + bias;
        }
    }
    __syncthreads();
    // pack fp8 + coalesced 16B stores: 16 threads per node row
    #pragma unroll
    for (int i = 0; i < 8; ++i) {
        int row = i * 16 + (tid >> 4);
        int node = base + row;
        if (node < N_NODES) {
            const float* src = &sm.Cs[row * 256 + (tid & 15) * 16];
            uvec4 outv;
            #pragma unroll
            for (int d = 0; d < 4; ++d) {
                int w = __builtin_amdgcn_cvt_pk_fp8_f32(src[d * 4 + 0], src[d * 4 + 1], 0, false);
                w     = __builtin_amdgcn_cvt_pk_fp8_f32(src[d * 4 + 2], src[d * 4 + 3], w, true);
                outv[d] = (unsigned)w;
            }
            *(uvec4*)(P + (size_t)node * 256 + (tid & 15) * 16) = outv;
        }
    }
}

// ---- edge kernel: gather fp8 P -> add+silu (A-frags in reg) -> W2 MFMA -> phi -> scatter ----
// launch_bounds (256,2): VGPR cap 256, natural demand ~128 -> 4 waves/SIMD, NO SPILL.
// (256,4) in round 5 forced VGPR=64 -> ~800 MB scratch spill traffic, 2x regression.
__global__ __launch_bounds__(256, 2) void egnn_edge_p(
    const u8* __restrict__ P, const void* __restrict__ coord_diff,
    const void* __restrict__ edge_attr, const void* __restrict__ edge_index,
    const u16* __restrict__ w1lb, const void* __restrict__ b2,
    const void* __restrict__ W3, const u16* __restrict__ W2t,
    float* __restrict__ agg, const int* __restrict__ flags)
{
    __shared__ __align__(16) u16 W2f[16384];   // frag-ordered W2 (32 KB)
    const int tid = threadIdx.x;
    #pragma unroll
    for (int i = 0; i < 8; ++i) {              // stage: f = t*512+ks*64+hi*32+l31, dst=f*8
        int f = i * 256 + tid;
        int t = f >> 9, ks = (f >> 6) & 7, fh = (f >> 5) & 1, fl = f & 31;
        *(svec8*)(&W2f[f * 8]) = *(const svec8*)(W2t + (t * 32 + fl) * 128 + ks * 16 + fh * 8);
    }
    const int is_bf = flags[0], is_i64 = flags[1];
    const int lane = tid & 63, wv = tid >> 6, l31 = lane & 31, hi = lane >> 5;
    __syncthreads();                           // last barrier; main loop is wave-autonomous

    uvec4 w1l[8];
    #pragma unroll
    for (int ks = 0; ks < 8; ++ks) w1l[ks] = *(const uvec4*)(w1lb + ks * 16 + hi * 8);
    float b2c[4], w3c[4];
    #pragma unroll
    for (int t = 0; t < 4; ++t) {
        int c = t * 32 + l31;
        b2c[t] = ldf(b2, c, is_bf);
        w3c[t] = ldf(W3, c, is_bf);
    }

    const int wid = blockIdx.x * 4 + wv, nw = gridDim.x * 4;
    for (int g = wid; g < NGROUP; g += nw) {
        const int e   = g * 32 + l31;
        const int row = ldi(edge_index, (size_t)e, is_i64);
        const int col = ldi(edge_index, (size_t)E_EDGES + e, is_i64);
        const float ea = ldf(edge_attr, (size_t)e, is_bf);

        uvec2 p1[8], p2[8];
        #pragma unroll
        for (int ks = 0; ks < 8; ++ks) {
            const int kk = ks * 16 + hi * 8;
            p1[ks] = *(const uvec2*)(P + (size_t)row * 256 + kk);
            p2[ks] = *(const uvec2*)(P + (size_t)col * 256 + 128 + kk);
        }
        frag_u af[8];
        #pragma unroll
        for (int ks = 0; ks < 8; ++ks) {
            float q1[8], q2[8];
            #pragma unroll
            for (int d = 0; d < 2; ++d) {
                fvec2 t0 = __builtin_amdgcn_cvt_pk_f32_fp8((int)p1[ks][d], false);
                fvec2 t1 = __builtin_amdgcn_cvt_pk_f32_fp8((int)p1[ks][d], true);
                q1[d * 4 + 0] = t0[0]; q1[d * 4 + 1] = t0[1];
                q1[d * 4 + 2] = t1[0]; q1[d * 4 + 3] = t1[1];
                fvec2 s0 = __builtin_amdgcn_cvt_pk_f32_fp8((int)p2[ks][d], false);
                fvec2 s1 = __builtin_amdgcn_cvt_pk_f32_fp8((int)p2[ks][d], true);
                q2[d * 4 + 0] = s0[0]; q2[d * 4 + 1] = s0[1];
                q2[d * 4 + 2] = s1[0]; q2[d * 4 + 3] = s1[1];
            }
            #pragma unroll
            for (int p = 0; p < 4; ++p) {
                const unsigned uw = w1l[ks][p];
                float xl = q1[2 * p]     + q2[2 * p]     + ea * lo16(uw);
                float xh = q1[2 * p + 1] + q2[2 * p + 1] + ea * hi16(uw);
                float yl = silu_f(xl), yh = silu_f(xh);
                af[ks].u[p] = (f2u(yl) >> 16) | (f2u(yh) & 0xFFFF0000u);  // trunc pack
            }
        }
        fvec16 acc[4] = {};
        #pragma unroll
        for (int ks = 0; ks < 8; ++ks) {
            #pragma unroll
            for (int t = 0; t < 4; ++t) {
                svec8 bf = *(const svec8*)(&W2f[((t * 8 + ks) * 2 + hi) * 256 + l31 * 8]);
                acc[t] = __builtin_amdgcn_mfma_f32_32x32x16_bf16(af[ks].s, bf, acc[t], 0, 0, 0);
            }
        }
        float s[16];
        #pragma unroll
        for (int r = 0; r < 16; ++r) s[r] = 0.0f;
        #pragma unroll
        for (int t = 0; t < 4; ++t)
            #pragma unroll
            for (int r = 0; r < 16; ++r)
                s[r] += silu_f(acc[t][r] + b2c[t]) * w3c[t];
        #pragma unroll
        for (int r = 0; r < 16; ++r) {          // butterfly over each 32-lane half
            s[r] += __shfl_xor(s[r], 1);
            s[r] += __shfl_xor(s[r], 2);
            s[r] += __shfl_xor(s[r], 4);
            s[r] += __shfl_xor(s[r], 8);
            s[r] += __shfl_xor(s[r], 16);
        }
        float phi = 0.0f;
        #pragma unroll
        for (int r = 0; r < 16; ++r) if (l31 == r) phi = s[r];
        if (l31 < 16) {
            const int em = (l31 & 3) + 8 * (l31 >> 2) + 4 * hi;   // C-layout row
            const int eg = g * 32 + em;
            const int r2 = ldi(edge_index, (size_t)eg, is_i64);
            const float cx = ldf(coord_diff, (size_t)eg * 3 + 0, is_bf);
            const float cy = ldf(coord_diff, (size_t)eg * 3 + 1, is_bf);
            const float cz = ldf(coord_diff, (size_t)eg * 3 + 2, is_bf);
            atomicAdd(&agg[r2 * 3 + 0], cx * phi);
            atomicAdd(&agg[r2 * 3 + 1], cy * phi);
            atomicAdd(&agg[r2 * 3 + 2], cz * phi);
        }
    }
}

// ================= fallback (round-3, verified) when ws too small =================
__global__ __launch_bounds__(256, 2) void egnn_edge_kernel(
    const void* __restrict__ h, const void* __restrict__ coord_diff,
    const void* __restrict__ edge_attr, const void* __restrict__ edge_index,
    const void* __restrict__ W1, const void* __restrict__ b1,
    const void* __restrict__ b2, const void* __restrict__ W3,
    const u16* __restrict__ W1t, const u16* __restrict__ W2t,
    float* __restrict__ agg, const int* __restrict__ flags)
{
    __shared__ __align__(16) u16 Xs[BE * XS_STRIDE];
    __shared__ int   rows_s[BE];
    __shared__ int   cols_s[BE];
    __shared__ float ea_s[BE];
    __shared__ float b1_s[HID], b2_s[HID], w1l_s[HID], w3_s[HID];

    const int tid = threadIdx.x;
    const int e0  = blockIdx.x * BE;
    const int is_bf  = flags[0];
    const int is_i64 = flags[1];

    if (tid < BE) {
        rows_s[tid] = ldi(edge_index, (size_t)(e0 + tid), is_i64);
        cols_s[tid] = ldi(edge_index, (size_t)(E_EDGES + e0 + tid), is_i64);
        ea_s[tid]   = ldf(edge_attr, (size_t)(e0 + tid), is_bf);
    }
    if (tid < HID) {
        b1_s[tid]  = ldf(b1, tid, is_bf);
        b2_s[tid]  = ldf(b2, tid, is_bf);
        w1l_s[tid] = ldf(W1, (size_t)256 * 128 + tid, is_bf);
        w3_s[tid]  = ldf(W3, tid, is_bf);
    }
    __syncthreads();
    {
        const int gg = tid >> 4, c = tid & 15;
        #pragma unroll
        for (int it = 0; it < 16; ++it) {
            int hr = it * 16 + gg;
            int e = hr >> 1, half = hr & 1;
            int src = half ? cols_s[e] : rows_s[e];
            svec8 v;
            if (is_bf) {
                v = *(const svec8*)((const u16*)h + (size_t)src * HID + c * 8);
            } else {
                const float* hf = (const float*)h + (size_t)src * HID + c * 8;
                float4 va = *(const float4*)hf;
                float4 vb = *(const float4*)(hf + 4);
                v[0] = (short)f2bf(va.x); v[1] = (short)f2bf(va.y);
                v[2] = (short)f2bf(va.z); v[3] = (short)f2bf(va.w);
                v[4] = (short)f2bf(vb.x); v[5] = (short)f2bf(vb.y);
                v[6] = (short)f2bf(vb.z); v[7] = (short)f2bf(vb.w);
            }
            *(svec8*)(&Xs[e * XS_STRIDE + half * 128 + c * 8]) = v;
        }
    }
    __syncthreads();
    const int lane = tid & 63;
    const int wv   = tid >> 6;
    const int l31  = lane & 31, hi = lane >> 5;
    const int col  = wv * 32 + l31;

    fvec16 acc[4] = {};
    for (int ks = 0; ks < 16; ++ks) {
        const int kk = ks * 16 + hi * 8;
        svec8 bfrag = *(const svec8*)(W1t + col * 256 + kk);
        #pragma unroll
        for (int mt = 0; mt < 4; ++mt) {
            svec8 afrag = *(const svec8*)(&Xs[(mt * 32 + l31) * XS_STRIDE + kk]);
            acc[mt] = __builtin_amdgcn_mfma_f32_32x32x16_bf16(afrag, bfrag, acc[mt], 0, 0, 0);
        }
    }
    __syncthreads();
    u16* Ys = Xs;
    #pragma unroll
    for (int mt = 0; mt < 4; ++mt)
        #pragma unroll
        for (int r = 0; r < 16; ++r) {
            int row = mt * 32 + (r & 3) + 8 * (r >> 2) + 4 * hi;
            float v = acc[mt][r] + ea_s[row] * w1l_s[col] + b1_s[col];
            Ys[row * YS_STRIDE + col] = f2bf(silu_f(v));
        }
    __syncthreads();
    fvec16 acc2[4] = {};
    for (int ks = 0; ks < 8; ++ks) {
        const int kk = ks * 16 + hi * 8;
        svec8 bfrag = *(const svec8*)(W2t + col * 128 + kk);
        #pragma unroll
        for (int mt = 0; mt < 4; ++mt) {
            svec8 afrag = *(const svec8*)(&Ys[(mt * 32 + l31) * YS_STRIDE + kk]);
            acc2[mt] = __builtin_amdgcn_mfma_f32_32x32x16_bf16(afrag, bfrag, acc2[mt], 0, 0, 0);
        }
    }
    __syncthreads();
    #pragma unroll
    for (int mt = 0; mt < 4; ++mt)
        #pragma unroll
        for (int r = 0; r < 16; ++r) {
            int row = mt * 32 + (r & 3) + 8 * (r >> 2) + 4 * hi;
            float v = acc2[mt][r] + b2_s[col];
            Ys[row * YS_STRIDE + col] = f2bf(silu_f(v));
        }
    __syncthreads();
    if (tid < BE) {
        const int e = tid;
        float phi = 0.0f;
        #pragma unroll
        for (int j = 0; j < 16; ++j) {
            svec8 x = *(const svec8*)(&Ys[e * YS_STRIDE + j * 8]);
            #pragma unroll
            for (int t = 0; t < 8; ++t)
                phi += bf2f((u16)x[t]) * w3_s[j * 8 + t];
        }
        const size_t ei = (size_t)(e0 + e);
        const int r = rows_s[e];
        atomicAdd(&agg[r * 3 + 0], ldf(coord_diff, ei * 3 + 0, is_bf) * phi);
        atomicAdd(&agg[r * 3 + 1], ldf(coord_diff, ei * 3 + 1, is_bf) * phi);
        atomicAdd(&agg[r * 3 + 2], ldf(coord_diff, ei * 3 + 2, is_bf) * phi);
    }
}

// ---- finalize: out = coord + agg/100, written in the input float dtype ----
__global__ void finalize_kernel(const void* __restrict__ coord,
                                const float* __restrict__ agg,
                                void* __restrict__ out,
                                const int* __restrict__ flags) {
    const int is_bf = flags[0];
    int i = blockIdx.x * blockDim.x + threadIdx.x;
    if (i < N_NODES * 3) {
        float v = ldf(coord, i, is_bf) + agg[i] * 0.01f;
        if (is_bf) ((u16*)out)[i] = f2bf(v);
        else       ((float*)out)[i] = v;
    }
}

extern "C" void kernel_launch(void* const* d_in, const int* in_sizes, int n_in,
                              void* d_out, int out_size, void* d_ws, size_t ws_size,
                              hipStream_t stream) {
    const void* h          = d_in[0];
    const void* coord      = d_in[1];
    const void* coord_diff = d_in[2];
    // d_in[3] = coord_cross (unused)
    const void* edge_attr  = d_in[4];
    const void* edge_index = d_in[5];
    const void* W1 = d_in[6];
    const void* b1 = d_in[7];
    const void* W2 = d_in[8];
    const void* b2 = d_in[9];
    const void* W3 = d_in[10];

    char* ws    = (char*)d_ws;
    float* agg  = (float*)ws;                        // 600000 B
    u16* W1t    = (u16*)(ws + 600064);               // 65536 B
    u16* W2t    = (u16*)(ws + 665600);               // 32768 B
    int* flags  = (int*)(ws + 698368);               // 16 B
    u16* w1lb   = (u16*)(ws + 698432);               // 256 B
    u8* P       = (u8*)(ws + 698880);                // 12,800,000 B (fp8)
    const size_t NEED = 698880 + (size_t)N_NODES * 256;

    detect_kernel<<<dim3(1), dim3(256), 0, stream>>>(h, edge_index, flags);
    hipMemsetAsync(agg, 0, N_NODES * 3 * sizeof(float), stream);
    transpose_w<<<dim3(128), dim3(256), 0, stream>>>(W1, W2, W1t, W2t, w1lb, flags);

    if (ws_size >= NEED) {
        precompute_p<<<dim3((N_NODES + 127) / 128), dim3(256), 0, stream>>>(
            h, b1, W1t, flags, P);
        egnn_edge_p<<<dim3(1024), dim3(256), 0, stream>>>(
            P, coord_diff, edge_attr, edge_index, w1lb, b2, W3, W2t, agg, flags);
    } else {
        egnn_edge_kernel<<<dim3(E_EDGES / BE), dim3(256), 0, stream>>>(
            h, coord_diff, edge_attr, edge_index, W1, b1, b2, W3, W1t, W2t, agg, flags);
    }
    finalize_kernel<<<dim3((N_NODES * 3 + 255) / 256), dim3(256), 0, stream>>>(coord, agg, d_out, flags);
}